// Round 3
// baseline (201.806 us; speedup 1.0000x reference)
//
#include <hip/hip_runtime.h>
#include <hip/hip_bf16.h>
#include <stdint.h>
#include <stddef.h>

// Problem: x[8192,512] fp32; Wq/Wk/Wv[64,512] fp32.
// q=x@Wq.T k=x@Wk.T v=x@Wv.T ; out = softmax(q k^T / 8) v  -> fp32 [8192,64]
//
// Strategy: bf16 MFMA everywhere (threshold is bf16-level 1.05e-3).
//  K1: project Q,K (row-major, Q pre-scaled by 0.125*log2e) and V^T into ws.
//  K2: flash attention, 64 Qblocks x 8 KV-splits; swapped QK^T so P feeds
//      mfma_16x16x16 PV directly without cross-lane traffic.
//  K3: combine the 8 KV-split partials.

#define SEQ    8192
#define DIN    512
#define NSPLIT 8
#define KVPER  (SEQ / NSPLIT)              // 1024
#define QK_SCALE 0.18033688011112042f      // 0.125 * log2(e)

typedef __attribute__((ext_vector_type(4))) float f32x4;
typedef __attribute__((ext_vector_type(4))) short s16x4;
typedef __attribute__((ext_vector_type(8))) short s16x8;

__device__ __forceinline__ short bf16s(float f) {
  unsigned u = __builtin_bit_cast(unsigned, f);
  u = (u + 0x7fffu + ((u >> 16) & 1u)) >> 16;   // RNE (finite inputs)
  return (short)u;
}

__device__ __forceinline__ s16x8 cvt8(f32x4 a, f32x4 b) {
  s16x8 r;
  r[0]=bf16s(a[0]); r[1]=bf16s(a[1]); r[2]=bf16s(a[2]); r[3]=bf16s(a[3]);
  r[4]=bf16s(b[0]); r[5]=bf16s(b[1]); r[6]=bf16s(b[2]); r[7]=bf16s(b[3]);
  return r;
}

// ---------------- Kernel 1: QKV projection ----------------
// 1536 wave-tasks: task = 512*mat + rowtile. Each wave: 16 rows x 64 cols,
// K=512 via 16 k-steps of mfma_f32_16x16x32_bf16.
// A-frag: row = lane&15, k = (lane>>4)*8 + j  (8 contiguous fp32 -> bf16)
// B-frag: col = lane&15 (=W row n), k likewise (W row-major contiguous)
// C:      col = lane&15 (=n), row = (lane>>4)*4 + r (= x row)
__global__ __launch_bounds__(256) void qkv_proj(
    const float* __restrict__ x,
    const float* __restrict__ Wq, const float* __restrict__ Wk,
    const float* __restrict__ Wv,
    short* __restrict__ Qo, short* __restrict__ Ko, short* __restrict__ VTo)
{
  const int wv   = threadIdx.x >> 6;
  const int lane = threadIdx.x & 63;
  const int qn   = lane & 15;
  const int g    = lane >> 4;
  const int tid  = blockIdx.x * 4 + wv;
  const int mat  = tid >> 9;          // 0=Q 1=K 2=V
  const int rt   = tid & 511;
  const int row0 = rt << 4;

  const float* W  = (mat == 0) ? Wq : (mat == 1) ? Wk : Wv;
  const float* xr = x + (size_t)(row0 + qn) * DIN + g * 8;
  const float* wr = W + (size_t)qn * DIN + g * 8;

  f32x4 acc[4] = {};

  for (int ks = 0; ks < 16; ++ks) {
    const float* xp = xr + ks * 32;
    s16x8 af = cvt8(*(const f32x4*)xp, *(const f32x4*)(xp + 4));
#pragma unroll
    for (int nt = 0; nt < 4; ++nt) {
      const float* wp = wr + (size_t)nt * 16 * DIN + ks * 32;
      s16x8 bf = cvt8(*(const f32x4*)wp, *(const f32x4*)(wp + 4));
      acc[nt] = __builtin_amdgcn_mfma_f32_16x16x32_bf16(af, bf, acc[nt], 0, 0, 0);
    }
  }

  if (mat < 2) {
    short* O = (mat == 0) ? Qo : Ko;
    const float sc = (mat == 0) ? QK_SCALE : 1.0f;
#pragma unroll
    for (int nt = 0; nt < 4; ++nt) {
#pragma unroll
      for (int r = 0; r < 4; ++r) {
        int row = row0 + 4 * g + r;
        int col = nt * 16 + qn;
        O[(size_t)row * 64 + col] = bf16s(acc[nt][r] * sc);
      }
    }
  } else {
    // V^T[d][t]; per nt: d = nt*16+qn fixed, t = row0+4g+r contiguous -> 8B store
#pragma unroll
    for (int nt = 0; nt < 4; ++nt) {
      int d = nt * 16 + qn;
      int t = row0 + 4 * g;
      s16x4 pk;
#pragma unroll
      for (int r = 0; r < 4; ++r) pk[r] = bf16s(acc[nt][r]);
      *(s16x4*)(VTo + (size_t)d * SEQ + t) = pk;
    }
  }
}

// ---------------- Kernel 2: flash attention partials ----------------
// Block: 4 waves x 32 q-rows = 128 q-rows; blockIdx: qblk = bid&63, split = bid>>6.
// Per KV chunk of 32:
//   S^T(tile 16t x 16q) = mfma_16x16x32(K_frag, Q_frag) x2 ksteps:
//     lane holds S[t=tt*16+4g+r][q=lane&15]  (exp2-domain, scale folded into Q)
//   online softmax: 4-lane shfl_xor(16,32) row-reduce; p stays lane-local and
//   is exactly the B-operand (k=4g+j) of mfma_f32_16x16x16bf16_1k.
//   PV: O^T[d][q] += V^T_frag(A: row=d_local, k=4g+j from VT 8B loads) @ P^T
__global__ __launch_bounds__(256) void attn_partial(
    const short* __restrict__ Q, const short* __restrict__ K,
    const short* __restrict__ VT,
    float* __restrict__ Op, float* __restrict__ mp, float* __restrict__ lp)
{
  const int lane  = threadIdx.x & 63;
  const int wv    = threadIdx.x >> 6;
  const int qn    = lane & 15;
  const int g     = lane >> 4;
  const int qblk  = blockIdx.x & 63;
  const int split = blockIdx.x >> 6;
  const int qbase = qblk * 128 + wv * 32;

  s16x8 Qf[2][2];
#pragma unroll
  for (int qt = 0; qt < 2; ++qt)
#pragma unroll
    for (int ks = 0; ks < 2; ++ks)
      Qf[qt][ks] = *(const s16x8*)(Q + (size_t)(qbase + qt * 16 + qn) * 64 + ks * 32 + g * 8);

  f32x4 acc[2][4] = {};
  float m_run[2] = {-1e30f, -1e30f};
  float l_run[2] = {0.f, 0.f};

  const int t00 = split * KVPER;
  for (int c = 0; c < KVPER / 32; ++c) {
    const int t0 = t00 + c * 32;

    s16x8 Kf[2][2];
#pragma unroll
    for (int tt = 0; tt < 2; ++tt)
#pragma unroll
      for (int ks = 0; ks < 2; ++ks)
        Kf[tt][ks] = *(const s16x8*)(K + (size_t)(t0 + tt * 16 + qn) * 64 + ks * 32 + g * 8);

    f32x4 s[2][2];
#pragma unroll
    for (int qt = 0; qt < 2; ++qt)
#pragma unroll
      for (int tt = 0; tt < 2; ++tt) {
        f32x4 a = {};
        a = __builtin_amdgcn_mfma_f32_16x16x32_bf16(Kf[tt][0], Qf[qt][0], a, 0, 0, 0);
        a = __builtin_amdgcn_mfma_f32_16x16x32_bf16(Kf[tt][1], Qf[qt][1], a, 0, 0, 0);
        s[qt][tt] = a;
      }

    s16x4 Vf[2][4];
#pragma unroll
    for (int tt = 0; tt < 2; ++tt)
#pragma unroll
      for (int db = 0; db < 4; ++db)
        Vf[tt][db] = *(const s16x4*)(VT + (size_t)(db * 16 + qn) * SEQ + t0 + tt * 16 + 4 * g);

#pragma unroll
    for (int qt = 0; qt < 2; ++qt) {
      float mx = s[qt][0][0];
#pragma unroll
      for (int i = 1; i < 4; ++i) mx = fmaxf(mx, s[qt][0][i]);
#pragma unroll
      for (int i = 0; i < 4; ++i) mx = fmaxf(mx, s[qt][1][i]);
      mx = fmaxf(mx, __shfl_xor(mx, 16));
      mx = fmaxf(mx, __shfl_xor(mx, 32));
      const float mnew = fmaxf(m_run[qt], mx);
      const float sc = exp2f(m_run[qt] - mnew);

      float ps = 0.f;
      s16x4 pb[2];
#pragma unroll
      for (int tt = 0; tt < 2; ++tt)
#pragma unroll
        for (int i = 0; i < 4; ++i) {
          float p = exp2f(s[qt][tt][i] - mnew);
          ps += p;
          pb[tt][i] = bf16s(p);
        }
      ps += __shfl_xor(ps, 16);
      ps += __shfl_xor(ps, 32);
      l_run[qt] = l_run[qt] * sc + ps;
      m_run[qt] = mnew;

#pragma unroll
      for (int db = 0; db < 4; ++db) {
        acc[qt][db][0] *= sc; acc[qt][db][1] *= sc;
        acc[qt][db][2] *= sc; acc[qt][db][3] *= sc;
      }
#pragma unroll
      for (int tt = 0; tt < 2; ++tt)
#pragma unroll
        for (int db = 0; db < 4; ++db)
          acc[qt][db] = __builtin_amdgcn_mfma_f32_16x16x16bf16_1k(
              Vf[tt][db], pb[tt], acc[qt][db], 0, 0, 0);
    }
  }

#pragma unroll
  for (int qt = 0; qt < 2; ++qt) {
    const int qrow = qbase + qt * 16 + qn;
#pragma unroll
    for (int db = 0; db < 4; ++db)
      *(f32x4*)(Op + ((size_t)split * SEQ + qrow) * 64 + db * 16 + 4 * g) = acc[qt][db];
    if (g == 0) {
      mp[split * SEQ + qrow] = m_run[qt];
      lp[split * SEQ + qrow] = l_run[qt];
    }
  }
}

// ---------------- Kernel 3: combine splits ----------------
__global__ __launch_bounds__(256) void attn_combine(
    const float* __restrict__ Op, const float* __restrict__ mp,
    const float* __restrict__ lp, float* __restrict__ out)
{
  const int idx  = blockIdx.x * 256 + threadIdx.x;   // 8192*16
  const int qrow = idx >> 4;
  const int d0   = (idx & 15) << 2;

  float ms[NSPLIT];
  float M = -1e30f;
#pragma unroll
  for (int s = 0; s < NSPLIT; ++s) {
    ms[s] = mp[s * SEQ + qrow];
    M = fmaxf(M, ms[s]);
  }
  float lsum = 0.f;
  f32x4 o = {};
#pragma unroll
  for (int s = 0; s < NSPLIT; ++s) {
    const float w = exp2f(ms[s] - M);
    lsum += w * lp[s * SEQ + qrow];
    f32x4 ov = *(const f32x4*)(Op + ((size_t)s * SEQ + qrow) * 64 + d0);
    o[0] += w * ov[0]; o[1] += w * ov[1]; o[2] += w * ov[2]; o[3] += w * ov[3];
  }
  const float inv = 1.0f / lsum;
  f32x4 r = {o[0] * inv, o[1] * inv, o[2] * inv, o[3] * inv};
  *(f32x4*)(out + (size_t)qrow * 64 + d0) = r;
}

extern "C" void kernel_launch(void* const* d_in, const int* in_sizes, int n_in,
                              void* d_out, int out_size, void* d_ws, size_t ws_size,
                              hipStream_t stream) {
  const float* x  = (const float*)d_in[0];
  const float* Wq = (const float*)d_in[1];
  const float* Wk = (const float*)d_in[2];
  const float* Wv = (const float*)d_in[3];
  float* out = (float*)d_out;

  char* ws = (char*)d_ws;
  short* Qb = (short*)(ws);                         // 1 MiB
  short* Kb = (short*)(ws + (1u << 20));            // 1 MiB
  short* VT = (short*)(ws + (2u << 20));            // 1 MiB
  float* Op = (float*)(ws + (3u << 20));            // NSPLIT*8192*64*4 = 16 MiB
  float* mp = (float*)(ws + (19u << 20));           // 256 KiB
  float* lp = (float*)(ws + (19u << 20) + NSPLIT * SEQ * sizeof(float));

  qkv_proj<<<384, 256, 0, stream>>>(x, Wq, Wk, Wv, Qb, Kb, VT);
  attn_partial<<<512, 256, 0, stream>>>(Qb, Kb, VT, Op, mp, lp);
  attn_combine<<<512, 256, 0, stream>>>(Op, mp, lp, out);
}

// Round 6
// 198.396 us; speedup vs baseline: 1.0172x; 1.0172x over previous
//
#include <hip/hip_runtime.h>
#include <hip/hip_bf16.h>
#include <stdint.h>
#include <stddef.h>

// x[8192,512] fp32; Wq/Wk/Wv[64,512] fp32.
// out = softmax((x Wq^T)(x Wk^T)^T / 8) (x Wv^T)  -> fp32 [8192,64]
//
// R4: NSPLIT 8->16 (occupancy 21.7%->~45%: grid was the cap), defer-max
// (exact, THR=8), v_perm P-packing, unroll-2 KV loop.

#define SEQ    8192
#define DIN    512
#define QK_SCALE 0.18033688011112042f      // 0.125 * log2(e)

typedef __attribute__((ext_vector_type(4))) float f32x4;
typedef __attribute__((ext_vector_type(4))) short s16x4;
typedef __attribute__((ext_vector_type(8))) short s16x8;
typedef __attribute__((ext_vector_type(2))) unsigned u32x2;

__device__ __forceinline__ short bf16s(float f) {
  unsigned u = __builtin_bit_cast(unsigned, f);
  u = (u + 0x7fffu + ((u >> 16) & 1u)) >> 16;   // RNE
  return (short)u;
}

__device__ __forceinline__ s16x8 cvt8(f32x4 a, f32x4 b) {
  s16x8 r;
  r[0]=bf16s(a[0]); r[1]=bf16s(a[1]); r[2]=bf16s(a[2]); r[3]=bf16s(a[3]);
  r[4]=bf16s(b[0]); r[5]=bf16s(b[1]); r[6]=bf16s(b[2]); r[7]=bf16s(b[3]);
  return r;
}

// pack 2 fp32 -> 2 truncated bf16 in one v_perm_b32
__device__ __forceinline__ unsigned pk2(float hi, float lo) {
  return __builtin_amdgcn_perm(__builtin_bit_cast(unsigned, hi),
                               __builtin_bit_cast(unsigned, lo), 0x07060302u);
}

// ---------------- Kernel 1: QKV projection ----------------
__global__ __launch_bounds__(256) void qkv_proj(
    const float* __restrict__ x,
    const float* __restrict__ Wq, const float* __restrict__ Wk,
    const float* __restrict__ Wv,
    short* __restrict__ Qo, short* __restrict__ Ko, short* __restrict__ VTo)
{
  const int wv   = threadIdx.x >> 6;
  const int lane = threadIdx.x & 63;
  const int qn   = lane & 15;
  const int g    = lane >> 4;
  const int tid  = blockIdx.x * 4 + wv;
  const int mat  = tid >> 9;          // 0=Q 1=K 2=V
  const int rt   = tid & 511;
  const int row0 = rt << 4;

  const float* W  = (mat == 0) ? Wq : (mat == 1) ? Wk : Wv;
  const float* xr = x + (size_t)(row0 + qn) * DIN + g * 8;
  const float* wr = W + (size_t)qn * DIN + g * 8;

  f32x4 acc[4] = {};

  for (int ks = 0; ks < 16; ++ks) {
    const float* xp = xr + ks * 32;
    s16x8 af = cvt8(*(const f32x4*)xp, *(const f32x4*)(xp + 4));
#pragma unroll
    for (int nt = 0; nt < 4; ++nt) {
      const float* wp = wr + (size_t)nt * 16 * DIN + ks * 32;
      s16x8 bf = cvt8(*(const f32x4*)wp, *(const f32x4*)(wp + 4));
      acc[nt] = __builtin_amdgcn_mfma_f32_16x16x32_bf16(af, bf, acc[nt], 0, 0, 0);
    }
  }

  if (mat < 2) {
    short* O = (mat == 0) ? Qo : Ko;
    const float sc = (mat == 0) ? QK_SCALE : 1.0f;
#pragma unroll
    for (int nt = 0; nt < 4; ++nt)
#pragma unroll
      for (int r = 0; r < 4; ++r)
        O[(size_t)(row0 + 4 * g + r) * 64 + nt * 16 + qn] = bf16s(acc[nt][r] * sc);
  } else {
#pragma unroll
    for (int nt = 0; nt < 4; ++nt) {
      s16x4 pk;
#pragma unroll
      for (int r = 0; r < 4; ++r) pk[r] = bf16s(acc[nt][r]);
      *(s16x4*)(VTo + (size_t)(nt * 16 + qn) * SEQ + row0 + 4 * g) = pk;
    }
  }
}

// ---------------- Kernel 2: flash attention partials ----------------
template<int NS>
__global__ __launch_bounds__(256) void attn_partial(
    const short* __restrict__ Q, const short* __restrict__ K,
    const short* __restrict__ VT,
    float* __restrict__ Op, float* __restrict__ mp, float* __restrict__ lp)
{
  const int lane  = threadIdx.x & 63;
  const int wv    = threadIdx.x >> 6;
  const int qn    = lane & 15;
  const int g     = lane >> 4;
  const int qblk  = blockIdx.x & 63;
  const int split = blockIdx.x >> 6;
  const int qbase = qblk * 128 + wv * 32;

  s16x8 Qf[2][2];
#pragma unroll
  for (int qt = 0; qt < 2; ++qt)
#pragma unroll
    for (int ks = 0; ks < 2; ++ks)
      Qf[qt][ks] = *(const s16x8*)(Q + (size_t)(qbase + qt * 16 + qn) * 64 + ks * 32 + g * 8);

  f32x4 acc[2][4] = {};
  float m_run[2] = {-1e30f, -1e30f};
  float l_run[2] = {0.f, 0.f};

  const int t00 = split * (SEQ / NS);
#pragma unroll 2
  for (int c = 0; c < SEQ / NS / 32; ++c) {
    const int t0 = t00 + c * 32;

    s16x8 Kf[2][2];
#pragma unroll
    for (int tt = 0; tt < 2; ++tt)
#pragma unroll
      for (int ks = 0; ks < 2; ++ks)
        Kf[tt][ks] = *(const s16x8*)(K + (size_t)(t0 + tt * 16 + qn) * 64 + ks * 32 + g * 8);

    f32x4 s[2][2];
#pragma unroll
    for (int qt = 0; qt < 2; ++qt)
#pragma unroll
      for (int tt = 0; tt < 2; ++tt) {
        f32x4 a = {};
        a = __builtin_amdgcn_mfma_f32_16x16x32_bf16(Kf[tt][0], Qf[qt][0], a, 0, 0, 0);
        a = __builtin_amdgcn_mfma_f32_16x16x32_bf16(Kf[tt][1], Qf[qt][1], a, 0, 0, 0);
        s[qt][tt] = a;
      }

    s16x4 Vf[2][4];
#pragma unroll
    for (int tt = 0; tt < 2; ++tt)
#pragma unroll
      for (int db = 0; db < 4; ++db)
        Vf[tt][db] = *(const s16x4*)(VT + (size_t)(db * 16 + qn) * SEQ + t0 + tt * 16 + 4 * g);

#pragma unroll
    for (int qt = 0; qt < 2; ++qt) {
      float mx = s[qt][0][0];
#pragma unroll
      for (int i = 1; i < 4; ++i) mx = fmaxf(mx, s[qt][0][i]);
#pragma unroll
      for (int i = 0; i < 4; ++i) mx = fmaxf(mx, s[qt][1][i]);
      mx = fmaxf(mx, __shfl_xor(mx, 16));
      mx = fmaxf(mx, __shfl_xor(mx, 32));

      // defer-max: rescale only when some row's chunk-max exceeds m_run+8.
      // Exact math either way (p bounded by 2^8, fp32 accumulators).
      if (__any(mx - m_run[qt] > 8.0f)) {
        const float mnew = fmaxf(m_run[qt], mx);
        const float sc = exp2f(m_run[qt] - mnew);
        l_run[qt] *= sc;
#pragma unroll
        for (int db = 0; db < 4; ++db) {
          acc[qt][db][0] *= sc; acc[qt][db][1] *= sc;
          acc[qt][db][2] *= sc; acc[qt][db][3] *= sc;
        }
        m_run[qt] = mnew;
      }

      float pv[2][4];
      float ps = 0.f;
#pragma unroll
      for (int tt = 0; tt < 2; ++tt)
#pragma unroll
        for (int i = 0; i < 4; ++i) {
          pv[tt][i] = exp2f(s[qt][tt][i] - m_run[qt]);
          ps += pv[tt][i];
        }
      ps += __shfl_xor(ps, 16);
      ps += __shfl_xor(ps, 32);
      l_run[qt] += ps;

      s16x4 pb[2];
#pragma unroll
      for (int tt = 0; tt < 2; ++tt) {
        u32x2 w;
        w[0] = pk2(pv[tt][1], pv[tt][0]);
        w[1] = pk2(pv[tt][3], pv[tt][2]);
        pb[tt] = __builtin_bit_cast(s16x4, w);
      }

#pragma unroll
      for (int tt = 0; tt < 2; ++tt)
#pragma unroll
        for (int db = 0; db < 4; ++db)
          acc[qt][db] = __builtin_amdgcn_mfma_f32_16x16x16bf16_1k(
              Vf[tt][db], pb[tt], acc[qt][db], 0, 0, 0);
    }
  }

#pragma unroll
  for (int qt = 0; qt < 2; ++qt) {
    const int qrow = qbase + qt * 16 + qn;
#pragma unroll
    for (int db = 0; db < 4; ++db)
      *(f32x4*)(Op + ((size_t)split * SEQ + qrow) * 64 + db * 16 + 4 * g) = acc[qt][db];
    if (g == 0) {
      mp[split * SEQ + qrow] = m_run[qt];
      lp[split * SEQ + qrow] = l_run[qt];
    }
  }
}

// ---------------- Kernel 3: combine splits ----------------
template<int NS>
__global__ __launch_bounds__(256) void attn_combine(
    const float* __restrict__ Op, const float* __restrict__ mp,
    const float* __restrict__ lp, float* __restrict__ out)
{
  const int idx  = blockIdx.x * 256 + threadIdx.x;   // 8192*16
  const int qrow = idx >> 4;
  const int d0   = (idx & 15) << 2;

  float ms[NS];
  float M = -1e30f;
#pragma unroll
  for (int s = 0; s < NS; ++s) {
    ms[s] = mp[s * SEQ + qrow];
    M = fmaxf(M, ms[s]);
  }
  float lsum = 0.f;
  f32x4 o = {};
#pragma unroll
  for (int s = 0; s < NS; ++s) {
    const float w = exp2f(ms[s] - M);
    lsum += w * lp[s * SEQ + qrow];
    f32x4 ov = *(const f32x4*)(Op + ((size_t)s * SEQ + qrow) * 64 + d0);
    o[0] += w * ov[0]; o[1] += w * ov[1]; o[2] += w * ov[2]; o[3] += w * ov[3];
  }
  const float inv = 1.0f / lsum;
  f32x4 r = {o[0] * inv, o[1] * inv, o[2] * inv, o[3] * inv};
  *(f32x4*)(out + (size_t)qrow * 64 + d0) = r;
}

extern "C" void kernel_launch(void* const* d_in, const int* in_sizes, int n_in,
                              void* d_out, int out_size, void* d_ws, size_t ws_size,
                              hipStream_t stream) {
  const float* x  = (const float*)d_in[0];
  const float* Wq = (const float*)d_in[1];
  const float* Wk = (const float*)d_in[2];
  const float* Wv = (const float*)d_in[3];
  float* out = (float*)d_out;

  char* ws = (char*)d_ws;
  short* Qb = (short*)(ws);                         // 1 MiB
  short* Kb = (short*)(ws + (1u << 20));            // 1 MiB
  short* VT = (short*)(ws + (2u << 20));            // 1 MiB

  qkv_proj<<<384, 256, 0, stream>>>(x, Wq, Wk, Wv, Qb, Kb, VT);

  const size_t base = (size_t)3 << 20;
  const size_t need16 = base + (size_t)16 * SEQ * 64 * 4 + (size_t)2 * 16 * SEQ * 4;

  if (ws_size >= need16) {
    constexpr int NS = 16;
    float* Op = (float*)(ws + base);
    float* mp = (float*)(ws + base + (size_t)NS * SEQ * 64 * 4);
    float* lp = mp + (size_t)NS * SEQ;
    attn_partial<NS><<<64 * NS, 256, 0, stream>>>(Qb, Kb, VT, Op, mp, lp);
    attn_combine<NS><<<512, 256, 0, stream>>>(Op, mp, lp, out);
  } else {
    constexpr int NS = 8;
    float* Op = (float*)(ws + base);
    float* mp = (float*)(ws + base + (size_t)NS * SEQ * 64 * 4);
    float* lp = mp + (size_t)NS * SEQ;
    attn_partial<NS><<<64 * NS, 256, 0, stream>>>(Qb, Kb, VT, Op, mp, lp);
    attn_combine<NS><<<512, 256, 0, stream>>>(Op, mp, lp, out);
  }
}